// Round 18
// baseline (1919.381 us; speedup 1.0000x reference)
//
#include <hip/hip_runtime.h>

typedef __attribute__((ext_vector_type(8))) short short8;   // 8 bf16 in 4 VGPRs
typedef __attribute__((ext_vector_type(4))) float f32x4;
typedef unsigned short u16;

#define DEVI __device__ __forceinline__

DEVI u16 f2bf(float f) {
  unsigned u = __float_as_uint(f);
  unsigned r = (u + 0x7fffu + ((u >> 16) & 1u)) >> 16;   // RNE
  return (u16)r;
}

DEVI void gl2lds16(const void* g, void* l) {
  __builtin_amdgcn_global_load_lds((const __attribute__((address_space(1))) void*)g,
                                   (__attribute__((address_space(3))) void*)l, 16, 0, 0);
}

// stage bf16 tile ROWS x BKE (row-major, ld elems) into linear LDS via global_load_lds
template<int ROWS, int BKE, int NT>
DEVI void stage_bf16(const u16* __restrict__ g, int ld, u16* lds, int tid) {
  constexpr int CPR = BKE / 8;          // 16B chunks per row
  constexpr int CH  = ROWS * CPR;
  constexpr int NW  = NT / 64;
  const int wave = tid >> 6, lane = tid & 63;
#pragma unroll
  for (int i = 0; i < CH / NT; i++) {
    int c = (i * NW + wave) * 64 + lane;
    int row = c / CPR;
    int colb = (c % CPR) * 16;
    gl2lds16((const char*)g + (long)row * ld * 2 + colb, (char*)lds + (long)c * 16);
  }
}

// one K=32 MFMA step on LDS tiles A[*][BKE], B[*][BKE]; wave tile = (FM*16) x (FN*16)
template<int FM, int FN, int BKE>
DEVI void kstep(const u16* Alds, const u16* Blds, int lane, int wr, int wc, int kk,
                f32x4 (*acc)[FN]) {
  const int ro = lane & 15, ko = kk + (lane >> 4) * 8;
  short8 a[FM], b[FN];
#pragma unroll
  for (int m = 0; m < FM; m++) a[m] = *(const short8*)(Alds + (wr + m * 16 + ro) * BKE + ko);
#pragma unroll
  for (int n = 0; n < FN; n++) b[n] = *(const short8*)(Blds + (wc + n * 16 + ro) * BKE + ko);
#pragma unroll
  for (int m = 0; m < FM; m++)
#pragma unroll
    for (int n = 0; n < FN; n++)
      acc[m][n] = __builtin_amdgcn_mfma_f32_16x16x32_bf16(a[m], b[n], acc[m][n], 0, 0, 0);
}

// ---- fp32 -> bf16 conversion for up to 7 tensors ----
struct CvtArgs {
  const float* s[7];
  u16* d[7];
  int n8[7];
};

__global__ __launch_bounds__(256) void cvt_all(CvtArgs a) {
  const int t = blockIdx.y;
  const int n = a.n8[t];
  const float* __restrict__ s = a.s[t];
  u16* __restrict__ d = a.d[t];
  for (long i = blockIdx.x * 256 + threadIdx.x; i < n; i += (long)gridDim.x * 256) {
    float4 v0 = ((const float4*)s)[2 * i];
    float4 v1 = ((const float4*)s)[2 * i + 1];
    ushort4 h0, h1;
    h0.x = f2bf(v0.x); h0.y = f2bf(v0.y); h0.z = f2bf(v0.z); h0.w = f2bf(v0.w);
    h1.x = f2bf(v1.x); h1.y = f2bf(v1.y); h1.z = f2bf(v1.z); h1.w = f2bf(v1.w);
    ((ushort4*)d)[2 * i] = h0;
    ((ushort4*)d)[2 * i + 1] = h1;
  }
}

// ---- merged QKV projection (all-bf16, BK=32 m97 economics, r16-proven) ----
struct Biases { const float* p[3]; };

__global__ __launch_bounds__(256) void proj3_kernel(const u16* __restrict__ Xb,
                                                    const u16* __restrict__ Wb,
                                                    Biases bs,
                                                    u16* __restrict__ Outb) {
  __shared__ u16 Alds[128 * 32];   // 8 KB
  __shared__ u16 Blds[128 * 32];   // 8 KB -> 16 KB total
  const int tid = threadIdx.x, lane = tid & 63, w = tid >> 6;
  const int wr = (w >> 1) * 64, wc = (w & 1) * 64;
  const int z = blockIdx.z;
  const u16* X = Xb + (long)z * 8388608;
  const u16* W = Wb + (long)z * 1048576;
  const float* bias = bs.p[z];
  u16* Out = Outb + (long)z * 8388608;
  const long rowB = (long)blockIdx.x * 128;   // fast dim: A-tile L2 sharing per XCD
  const int colB = blockIdx.y * 128;
  f32x4 acc[4][4] = {};
  for (int k0 = 0; k0 < 1024; k0 += 32) {
    stage_bf16<128, 32, 256>(X + rowB * 1024 + k0, 1024, Alds, tid);
    stage_bf16<128, 32, 256>(W + (long)colB * 1024 + k0, 1024, Blds, tid);
    __syncthreads();
    kstep<4, 4, 32>(Alds, Blds, lane, wr, wc, 0, acc);
    __syncthreads();
  }
  const int ro = (lane >> 4) * 4, co = lane & 15;
  const float sc = (z == 0) ? 0.125f : 1.0f;
  if (z < 2) {
#pragma unroll
    for (int n = 0; n < 4; n++) {
      const int col = colB + wc + n * 16 + co;
      const float bv = bias[col];
      const int h = col >> 6, d = col & 63;
#pragma unroll
      for (int m = 0; m < 4; m++)
#pragma unroll
        for (int j = 0; j < 4; j++) {
          long r = rowB + wr + m * 16 + ro + j;
          long bq = r >> 10, s = r & 1023;
          Out[(((bq * 16 + h) * 1024 + s) << 6) + d] = f2bf((acc[m][n][j] + bv) * sc);
        }
    }
  } else {
    // transposed: Vt[bh][d][s], s contiguous over j -> ushort4 store
#pragma unroll
    for (int n = 0; n < 4; n++) {
      const int col = colB + wc + n * 16 + co;
      const float bv = bias[col];
      const long h = col >> 6, d = col & 63;
#pragma unroll
      for (int m = 0; m < 4; m++) {
        long r0 = rowB + wr + m * 16 + ro;
        long bq = r0 >> 10, s = r0 & 1023;
        ushort4 pk;
        pk.x = f2bf(acc[m][n][0] + bv);
        pk.y = f2bf(acc[m][n][1] + bv);
        pk.z = f2bf(acc[m][n][2] + bv);
        pk.w = f2bf(acc[m][n][3] + bv);
        *(ushort4*)(Out + (((bq * 16 + h) << 16) | (d << 10) | s)) = pk;
      }
    }
  }
}

// ---- fused flash (r13/r16 sync structure; attn streamed from Plds):
//      QBLK=128, 4 waves, 48 KB LDS. Pass 1: KVBLK=128 dbuf. Pass 2: KVBLK=64
//      K/V dbuf + P LDS round trip; attn tile written from Plds (bf16->fp32,
//      4x ds_read_b128 + 8x f32x4 NT stores/thread instead of 32 scalar
//      stores). End barrier: lgkmcnt(0) + vmcnt(8) + s_barrier
//      (retires 4 staging loads, keeps this iter's 8 NT stores in flight). ----
__global__ __launch_bounds__(256) void flash_kernel(const u16* __restrict__ Q,
                                                    const u16* __restrict__ K,
                                                    const u16* __restrict__ Vt,
                                                    float* __restrict__ attn,
                                                    u16* __restrict__ Ctx) {
  __shared__ u16 lds[24576];          // 48 KB
  u16* const Pl = lds + 16384;
  const int tid = threadIdx.x, lane = tid & 63, w = tid >> 6;
  const int z = blockIdx.x;                 // b*16+h
  const int rowB = blockIdx.y * 128;
  const int b = z >> 4, h = z & 15;
  const u16* Qb  = Q  + (long)z * 65536 + (long)rowB * 64;
  const u16* Kb  = K  + (long)z * 65536;
  const u16* Vtb = Vt + (long)z * 65536;
  const int ro = lane & 15, ko8 = (lane >> 4) * 8;
  const int qw = w * 32;                    // wave's q offset in tile

  // Q fragments resident in registers (Q pre-scaled by 0.125)
  short8 aq[2][2];
#pragma unroll
  for (int m = 0; m < 2; m++)
#pragma unroll
    for (int kt = 0; kt < 2; kt++)
      aq[m][kt] = *(const short8*)(Qb + (qw + m * 16 + ro) * 64 + kt * 32 + ko8);

  float lsum[8];
#pragma unroll
  for (int i = 0; i < 8; i++) lsum[i] = 0.0f;

  // ---- pass 1: l = sum exp(s); KVBLK=128 double-buffered ----
  stage_bf16<128, 64, 256>(Kb, 64, lds, tid);
  __syncthreads();
  for (int kb = 0; kb < 8; kb++) {
    const int cur = kb & 1;
    if (kb < 7) stage_bf16<128, 64, 256>(Kb + (kb + 1) * 8192, 64, lds + ((kb + 1) & 1) * 8192, tid);
    const u16* Kc = lds + cur * 8192;
    f32x4 acc[2][8] = {};
    __builtin_amdgcn_s_setprio(1);
#pragma unroll
    for (int kt = 0; kt < 2; kt++) {
      short8 bfr[8];
#pragma unroll
      for (int n = 0; n < 8; n++)
        bfr[n] = *(const short8*)(Kc + (n * 16 + ro) * 64 + kt * 32 + ko8);
#pragma unroll
      for (int m = 0; m < 2; m++)
#pragma unroll
        for (int n = 0; n < 8; n++)
          acc[m][n] = __builtin_amdgcn_mfma_f32_16x16x32_bf16(aq[m][kt], bfr[n], acc[m][n], 0, 0, 0);
    }
    __builtin_amdgcn_s_setprio(0);
#pragma unroll
    for (int m = 0; m < 2; m++)
#pragma unroll
      for (int j = 0; j < 4; j++) {
        const int i = m * 4 + j;
        float e0 = __expf(acc[m][0][j]) + __expf(acc[m][1][j]) +
                   __expf(acc[m][2][j]) + __expf(acc[m][3][j]);
        float e1 = __expf(acc[m][4][j]) + __expf(acc[m][5][j]) +
                   __expf(acc[m][6][j]) + __expf(acc[m][7][j]);
        lsum[i] += e0 + e1;
      }
    __syncthreads();   // drains prefetch + all reads of cur done before overwrite
  }

  // overlap pass-2's first staging with the linv reduction (post-barrier: safe)
  stage_bf16<64, 64, 256>(Kb, 64, lds, tid);                // K(0) -> Kd[0]
  stage_bf16<64, 64, 256>(Vtb, 1024, lds + 8192, tid);      // V(0) -> Vd[0]
  float linv[8];
#pragma unroll
  for (int i = 0; i < 8; i++) {
    float s = lsum[i];
#pragma unroll
    for (int o = 8; o > 0; o >>= 1) s += __shfl_xor(s, o, 64);
    linv[i] = 1.0f / s;
  }
  __syncthreads();   // staging drained + visible

  // ---- pass 2: recompute S, P->Plds, PV, then stream attn tile from Plds ----
  f32x4 acc_o[2][4] = {};
  float* ab = attn + ((long)z << 20) + (long)rowB * 1024;
  // per-thread copy geometry (wave-aligned: reads only this wave's 32 rows)
  const int cr  = qw + (lane >> 1);        // copy row
  const int chh = lane & 1;                // column half (0..1)
  for (int kb = 0; kb < 16; kb++) {
    const int cur = kb & 1, nxt = cur ^ 1;
    if (kb < 15) {
      stage_bf16<64, 64, 256>(Kb + (kb + 1) * 4096, 64, lds + nxt * 4096, tid);
      stage_bf16<64, 64, 256>(Vtb + (kb + 1) * 64, 1024, lds + 8192 + nxt * 4096, tid);
    }
    __builtin_amdgcn_sched_barrier(0);   // pin: staging loads issue first
    const u16* Kc = lds + cur * 4096;
    const u16* Vc = lds + 8192 + cur * 4096;
    f32x4 acc[2][4] = {};
    __builtin_amdgcn_s_setprio(1);
#pragma unroll
    for (int kt = 0; kt < 2; kt++) {
      short8 bfr[4];
#pragma unroll
      for (int n = 0; n < 4; n++)
        bfr[n] = *(const short8*)(Kc + (n * 16 + ro) * 64 + kt * 32 + ko8);
#pragma unroll
      for (int m = 0; m < 2; m++)
#pragma unroll
        for (int n = 0; n < 4; n++)
          acc[m][n] = __builtin_amdgcn_mfma_f32_16x16x32_bf16(aq[m][kt], bfr[n], acc[m][n], 0, 0, 0);
    }
    __builtin_amdgcn_s_setprio(0);
    // normalized P -> wave-private swizzled Plds (bf16); no global stores here
#pragma unroll
    for (int m = 0; m < 2; m++)
#pragma unroll
      for (int j = 0; j < 4; j++) {
        const int i = m * 4 + j;
        const int ql = qw + m * 16 + (lane >> 4) * 4 + j;   // own-wave q row
        u16* prow = Pl + ql * 64;
        const int sw = ((ql & 7) << 3);
#pragma unroll
        for (int n = 0; n < 4; n++) {
          const int col = n * 16 + (lane & 15);
          prow[col ^ sw] = f2bf(__expf(acc[m][n][j]) * linv[i]);
        }
      }
    // own-wave P writes visible (cross-lane within wave, lockstep)
    asm volatile("s_waitcnt lgkmcnt(0)" ::: "memory");
    __builtin_amdgcn_sched_barrier(0);
    // PV: acc_o += P(own rows, Plds) * V(Vc)
    __builtin_amdgcn_s_setprio(1);
#pragma unroll
    for (int kt = 0; kt < 2; kt++) {
      short8 pa[2], bv[4];
#pragma unroll
      for (int m = 0; m < 2; m++) {
        const int row = qw + m * 16 + ro;
        pa[m] = *(const short8*)(Pl + row * 64 + ((kt * 32 + ko8) ^ ((row & 7) << 3)));
      }
#pragma unroll
      for (int n = 0; n < 4; n++)
        bv[n] = *(const short8*)(Vc + (n * 16 + ro) * 64 + kt * 32 + ko8);
#pragma unroll
      for (int m = 0; m < 2; m++)
#pragma unroll
        for (int n = 0; n < 4; n++)
          acc_o[m][n] = __builtin_amdgcn_mfma_f32_16x16x32_bf16(pa[m], bv[n], acc_o[m][n], 0, 0, 0);
    }
    __builtin_amdgcn_s_setprio(0);
    // stream this tile's attn rows from Plds (bf16 -> fp32), vectorized:
    // 4x ds_read_b128 + 8x f32x4 NT stores per thread; reads stay within
    // this wave's rows (cr in [qw, qw+32)) -- lockstep + lgkmcnt covers it.
    {
      const u16* prow2 = Pl + cr * 64;
      float* gout = ab + (long)cr * 1024 + kb * 64 + chh * 32;
      const int swr = cr & 7;
#pragma unroll
      for (int g = 0; g < 4; g++) {
        const int a8 = chh * 4 + g;              // 8-col group index 0..7
        short8 v = *(const short8*)(prow2 + 8 * (a8 ^ swr));
        f32x4 f0, f1;
        f0.x = __uint_as_float((unsigned)(unsigned short)v[0] << 16);
        f0.y = __uint_as_float((unsigned)(unsigned short)v[1] << 16);
        f0.z = __uint_as_float((unsigned)(unsigned short)v[2] << 16);
        f0.w = __uint_as_float((unsigned)(unsigned short)v[3] << 16);
        f1.x = __uint_as_float((unsigned)(unsigned short)v[4] << 16);
        f1.y = __uint_as_float((unsigned)(unsigned short)v[5] << 16);
        f1.z = __uint_as_float((unsigned)(unsigned short)v[6] << 16);
        f1.w = __uint_as_float((unsigned)(unsigned short)v[7] << 16);
        __builtin_nontemporal_store(f0, (f32x4*)(gout + g * 8));
        __builtin_nontemporal_store(f1, (f32x4*)(gout + g * 8 + 4));
      }
    }
    // COUNTED end-of-iteration barrier: my ds reads done; my 4 staging loads
    // retired (vmcnt(8) leaves only the 8 newest = this iter's NT stores in
    // flight); then rendezvous. Tail kb=15: no loads issued, wait is a no-op.
    asm volatile("s_waitcnt lgkmcnt(0)" ::: "memory");
    __builtin_amdgcn_sched_barrier(0);
    asm volatile("s_waitcnt vmcnt(8)" ::: "memory");
    __builtin_amdgcn_s_barrier();
    __builtin_amdgcn_sched_barrier(0);
  }

  // write Ctx (B,S,E) bf16
  u16* cb = Ctx + ((long)b << 20) + (long)h * 64;
#pragma unroll
  for (int m = 0; m < 2; m++)
#pragma unroll
    for (int j = 0; j < 4; j++) {
      const long s = rowB + qw + m * 16 + (lane >> 4) * 4 + j;
#pragma unroll
      for (int n = 0; n < 4; n++)
        cb[s * 1024 + n * 16 + (lane & 15)] = f2bf(acc_o[m][n][j]);
    }
}

// ---- out projection (all-bf16, BK=32 m97 economics, r16-proven) ----
__global__ __launch_bounds__(256) void outb_kernel(const u16* __restrict__ Ctx,
                                                   const u16* __restrict__ W,
                                                   const float* __restrict__ bias,
                                                   float* __restrict__ Out) {
  __shared__ u16 Alds[128 * 32];
  __shared__ u16 Blds[128 * 32];
  const int tid = threadIdx.x, lane = tid & 63, w = tid >> 6;
  const int wr = (w >> 1) * 64, wc = (w & 1) * 64;
  const long rowB = (long)blockIdx.x * 128;   // fast dim
  const int colB = blockIdx.y * 128;
  f32x4 acc[4][4] = {};
  for (int k0 = 0; k0 < 1024; k0 += 32) {
    stage_bf16<128, 32, 256>(Ctx + rowB * 1024 + k0, 1024, Alds, tid);
    stage_bf16<128, 32, 256>(W + (long)colB * 1024 + k0, 1024, Blds, tid);
    __syncthreads();
    kstep<4, 4, 32>(Alds, Blds, lane, wr, wc, 0, acc);
    __syncthreads();
  }
  const int ro = (lane >> 4) * 4, co = lane & 15;
#pragma unroll
  for (int n = 0; n < 4; n++) {
    const int col = colB + wc + n * 16 + co;
    const float bv = bias[col];
#pragma unroll
    for (int m = 0; m < 4; m++)
#pragma unroll
      for (int j = 0; j < 4; j++) {
        long r = rowB + wr + m * 16 + ro + j;
        __builtin_nontemporal_store(acc[m][n][j] + bv, Out + r * 1024 + col);
      }
  }
}

extern "C" void kernel_launch(void* const* d_in, const int* in_sizes, int n_in,
                              void* d_out, int out_size, void* d_ws, size_t ws_size,
                              hipStream_t stream) {
  const float* query = (const float*)d_in[0];
  const float* key   = (const float*)d_in[1];
  const float* value = (const float*)d_in[2];
  const float* q_w   = (const float*)d_in[3];
  const float* q_b   = (const float*)d_in[4];
  const float* k_w   = (const float*)d_in[5];
  const float* k_b   = (const float*)d_in[6];
  const float* v_w   = (const float*)d_in[7];
  const float* v_b   = (const float*)d_in[8];
  const float* out_w = (const float*)d_in[9];
  const float* out_b = (const float*)d_in[10];

  const long MB = 1048576L;
  char* ws = (char*)d_ws;
  u16* Qp  = (u16*)(ws);             // (B,H,S,D) bf16 (0.125-scaled), 16 MB
  u16* Kp  = (u16*)(ws + 16 * MB);   // (B,H,S,D) 16 MB
  u16* Vt  = (u16*)(ws + 32 * MB);   // (B,H,D,S) 16 MB (written directly by proj z=2)
  u16* Qb  = (u16*)(ws + 48 * MB);   // bf16 query input   } consecutive, stride 16 MB
  u16* Kb  = (u16*)(ws + 64 * MB);   // bf16 key input     }
  u16* Vb  = (u16*)(ws + 80 * MB);   // bf16 value input   }
  u16* Ctx = (u16*)(ws + 64 * MB);   // (B,S,E) aliases Kb (dead after proj3)
  u16* Wq  = (u16*)(ws + 96 * MB);   // 2 MB each, consecutive
  u16* Wk  = (u16*)(ws + 98 * MB);
  u16* Wv  = (u16*)(ws + 100 * MB);
  u16* Wo  = (u16*)(ws + 102 * MB);  // total 104 MB

  float* attn = (float*)d_out;                       // [8,16,1024,1024]
  float* outp = (float*)d_out + 134217728L;          // [8,1024,1024]

  CvtArgs ca;
  ca.s[0] = query; ca.d[0] = Qb; ca.n8[0] = 1048576;
  ca.s[1] = key;   ca.d[1] = Kb; ca.n8[1] = 1048576;
  ca.s[2] = value; ca.d[2] = Vb; ca.n8[2] = 1048576;
  ca.s[3] = q_w;   ca.d[3] = Wq; ca.n8[3] = 131072;
  ca.s[4] = k_w;   ca.d[4] = Wk; ca.n8[4] = 131072;
  ca.s[5] = v_w;   ca.d[5] = Wv; ca.n8[5] = 131072;
  ca.s[6] = out_w; ca.d[6] = Wo; ca.n8[6] = 131072;

  Biases bs;
  bs.p[0] = q_b; bs.p[1] = k_b; bs.p[2] = v_b;

  cvt_all<<<dim3(2048, 7), dim3(256), 0, stream>>>(ca);
  proj3_kernel<<<dim3(64, 8, 3), dim3(256), 0, stream>>>(Qb, Wq, bs, Qp);
  flash_kernel<<<dim3(128, 8), dim3(256), 0, stream>>>(Qp, Kp, Vt, attn, Ctx);
  outb_kernel<<<dim3(64, 8), dim3(256), 0, stream>>>(Ctx, Wo, out_b, outp);
}

// Round 19
// 319.218 us; speedup vs baseline: 6.0128x; 6.0128x over previous
//
#include <hip/hip_runtime.h>

typedef __attribute__((ext_vector_type(8))) short short8;   // 8 bf16 in 4 VGPRs
typedef __attribute__((ext_vector_type(4))) float f32x4;
typedef unsigned short u16;

#define DEVI __device__ __forceinline__

DEVI u16 f2bf(float f) {
  unsigned u = __float_as_uint(f);
  unsigned r = (u + 0x7fffu + ((u >> 16) & 1u)) >> 16;   // RNE
  return (u16)r;
}

DEVI void gl2lds16(const void* g, void* l) {
  __builtin_amdgcn_global_load_lds((const __attribute__((address_space(1))) void*)g,
                                   (__attribute__((address_space(3))) void*)l, 16, 0, 0);
}

// stage bf16 tile ROWS x BKE (row-major, ld elems) into linear LDS via global_load_lds
template<int ROWS, int BKE, int NT>
DEVI void stage_bf16(const u16* __restrict__ g, int ld, u16* lds, int tid) {
  constexpr int CPR = BKE / 8;          // 16B chunks per row
  constexpr int CH  = ROWS * CPR;
  constexpr int NW  = NT / 64;
  const int wave = tid >> 6, lane = tid & 63;
#pragma unroll
  for (int i = 0; i < CH / NT; i++) {
    int c = (i * NW + wave) * 64 + lane;
    int row = c / CPR;
    int colb = (c % CPR) * 16;
    gl2lds16((const char*)g + (long)row * ld * 2 + colb, (char*)lds + (long)c * 16);
  }
}

// one K=32 MFMA step on LDS tiles A[*][BKE], B[*][BKE]; wave tile = (FM*16) x (FN*16)
template<int FM, int FN, int BKE>
DEVI void kstep(const u16* Alds, const u16* Blds, int lane, int wr, int wc, int kk,
                f32x4 (*acc)[FN]) {
  const int ro = lane & 15, ko = kk + (lane >> 4) * 8;
  short8 a[FM], b[FN];
#pragma unroll
  for (int m = 0; m < FM; m++) a[m] = *(const short8*)(Alds + (wr + m * 16 + ro) * BKE + ko);
#pragma unroll
  for (int n = 0; n < FN; n++) b[n] = *(const short8*)(Blds + (wc + n * 16 + ro) * BKE + ko);
#pragma unroll
  for (int m = 0; m < FM; m++)
#pragma unroll
    for (int n = 0; n < FN; n++)
      acc[m][n] = __builtin_amdgcn_mfma_f32_16x16x32_bf16(a[m], b[n], acc[m][n], 0, 0, 0);
}

// ---- fp32 -> bf16 conversion for up to 7 tensors ----
struct CvtArgs {
  const float* s[7];
  u16* d[7];
  int n8[7];
};

__global__ __launch_bounds__(256) void cvt_all(CvtArgs a) {
  const int t = blockIdx.y;
  const int n = a.n8[t];
  const float* __restrict__ s = a.s[t];
  u16* __restrict__ d = a.d[t];
  for (long i = blockIdx.x * 256 + threadIdx.x; i < n; i += (long)gridDim.x * 256) {
    float4 v0 = ((const float4*)s)[2 * i];
    float4 v1 = ((const float4*)s)[2 * i + 1];
    ushort4 h0, h1;
    h0.x = f2bf(v0.x); h0.y = f2bf(v0.y); h0.z = f2bf(v0.z); h0.w = f2bf(v0.w);
    h1.x = f2bf(v1.x); h1.y = f2bf(v1.y); h1.z = f2bf(v1.z); h1.w = f2bf(v1.w);
    ((ushort4*)d)[2 * i] = h0;
    ((ushort4*)d)[2 * i + 1] = h1;
  }
}

// ---- merged QKV projection (all-bf16, BK=32 m97 economics, r16-proven) ----
struct Biases { const float* p[3]; };

__global__ __launch_bounds__(256) void proj3_kernel(const u16* __restrict__ Xb,
                                                    const u16* __restrict__ Wb,
                                                    Biases bs,
                                                    u16* __restrict__ Outb) {
  __shared__ u16 Alds[128 * 32];   // 8 KB
  __shared__ u16 Blds[128 * 32];   // 8 KB -> 16 KB total
  const int tid = threadIdx.x, lane = tid & 63, w = tid >> 6;
  const int wr = (w >> 1) * 64, wc = (w & 1) * 64;
  const int z = blockIdx.z;
  const u16* X = Xb + (long)z * 8388608;
  const u16* W = Wb + (long)z * 1048576;
  const float* bias = bs.p[z];
  u16* Out = Outb + (long)z * 8388608;
  const long rowB = (long)blockIdx.x * 128;   // fast dim: A-tile L2 sharing per XCD
  const int colB = blockIdx.y * 128;
  f32x4 acc[4][4] = {};
  for (int k0 = 0; k0 < 1024; k0 += 32) {
    stage_bf16<128, 32, 256>(X + rowB * 1024 + k0, 1024, Alds, tid);
    stage_bf16<128, 32, 256>(W + (long)colB * 1024 + k0, 1024, Blds, tid);
    __syncthreads();
    kstep<4, 4, 32>(Alds, Blds, lane, wr, wc, 0, acc);
    __syncthreads();
  }
  const int ro = (lane >> 4) * 4, co = lane & 15;
  const float sc = (z == 0) ? 0.125f : 1.0f;
  if (z < 2) {
#pragma unroll
    for (int n = 0; n < 4; n++) {
      const int col = colB + wc + n * 16 + co;
      const float bv = bias[col];
      const int h = col >> 6, d = col & 63;
#pragma unroll
      for (int m = 0; m < 4; m++)
#pragma unroll
        for (int j = 0; j < 4; j++) {
          long r = rowB + wr + m * 16 + ro + j;
          long bq = r >> 10, s = r & 1023;
          Out[(((bq * 16 + h) * 1024 + s) << 6) + d] = f2bf((acc[m][n][j] + bv) * sc);
        }
    }
  } else {
    // transposed: Vt[bh][d][s], s contiguous over j -> ushort4 store
#pragma unroll
    for (int n = 0; n < 4; n++) {
      const int col = colB + wc + n * 16 + co;
      const float bv = bias[col];
      const long h = col >> 6, d = col & 63;
#pragma unroll
      for (int m = 0; m < 4; m++) {
        long r0 = rowB + wr + m * 16 + ro;
        long bq = r0 >> 10, s = r0 & 1023;
        ushort4 pk;
        pk.x = f2bf(acc[m][n][0] + bv);
        pk.y = f2bf(acc[m][n][1] + bv);
        pk.z = f2bf(acc[m][n][2] + bv);
        pk.w = f2bf(acc[m][n][3] + bv);
        *(ushort4*)(Out + (((bq * 16 + h) << 16) | (d << 10) | s)) = pk;
      }
    }
  }
}

// ---- fused flash (r13/r16-proven: QBLK=128, 4 waves, 48 KB LDS):
//      attn = softmax(Q.K^T) written once (scale folded into Q), Ctx = attn @ V.
//      Pass 1: KVBLK=128 dbuf + __syncthreads. Pass 2: KVBLK=64 K/V dbuf +
//      P LDS round trip + COUNTED end barrier (lgkmcnt0 + vmcnt(32) +
//      s_barrier): this iter's 32 NT attn stores stay in flight.
//      Attn stores stay SCALAR: per wave-instruction they form 4 rows x 64B
//      contiguous = full HBM granules (r18's f32x4 repack made 32x32B
//      fragments -> 2.6x write amplification + store-queue stall; reverted). ----
__global__ __launch_bounds__(256) void flash_kernel(const u16* __restrict__ Q,
                                                    const u16* __restrict__ K,
                                                    const u16* __restrict__ Vt,
                                                    float* __restrict__ attn,
                                                    u16* __restrict__ Ctx) {
  __shared__ u16 lds[24576];          // 48 KB
  u16* const Pl = lds + 16384;
  const int tid = threadIdx.x, lane = tid & 63, w = tid >> 6;
  const int z = blockIdx.x;                 // b*16+h
  const int rowB = blockIdx.y * 128;
  const int b = z >> 4, h = z & 15;
  const u16* Qb  = Q  + (long)z * 65536 + (long)rowB * 64;
  const u16* Kb  = K  + (long)z * 65536;
  const u16* Vtb = Vt + (long)z * 65536;
  const int ro = lane & 15, ko8 = (lane >> 4) * 8;
  const int qw = w * 32;                    // wave's q offset in tile

  // Q fragments resident in registers (Q pre-scaled by 0.125)
  short8 aq[2][2];
#pragma unroll
  for (int m = 0; m < 2; m++)
#pragma unroll
    for (int kt = 0; kt < 2; kt++)
      aq[m][kt] = *(const short8*)(Qb + (qw + m * 16 + ro) * 64 + kt * 32 + ko8);

  float lsum[8];
#pragma unroll
  for (int i = 0; i < 8; i++) lsum[i] = 0.0f;

  // ---- pass 1: l = sum exp(s); KVBLK=128 double-buffered ----
  stage_bf16<128, 64, 256>(Kb, 64, lds, tid);
  __syncthreads();
  for (int kb = 0; kb < 8; kb++) {
    const int cur = kb & 1;
    if (kb < 7) stage_bf16<128, 64, 256>(Kb + (kb + 1) * 8192, 64, lds + ((kb + 1) & 1) * 8192, tid);
    const u16* Kc = lds + cur * 8192;
    f32x4 acc[2][8] = {};
    __builtin_amdgcn_s_setprio(1);
#pragma unroll
    for (int kt = 0; kt < 2; kt++) {
      short8 bfr[8];
#pragma unroll
      for (int n = 0; n < 8; n++)
        bfr[n] = *(const short8*)(Kc + (n * 16 + ro) * 64 + kt * 32 + ko8);
#pragma unroll
      for (int m = 0; m < 2; m++)
#pragma unroll
        for (int n = 0; n < 8; n++)
          acc[m][n] = __builtin_amdgcn_mfma_f32_16x16x32_bf16(aq[m][kt], bfr[n], acc[m][n], 0, 0, 0);
    }
    __builtin_amdgcn_s_setprio(0);
#pragma unroll
    for (int m = 0; m < 2; m++)
#pragma unroll
      for (int j = 0; j < 4; j++) {
        const int i = m * 4 + j;
        float e0 = __expf(acc[m][0][j]) + __expf(acc[m][1][j]) +
                   __expf(acc[m][2][j]) + __expf(acc[m][3][j]);
        float e1 = __expf(acc[m][4][j]) + __expf(acc[m][5][j]) +
                   __expf(acc[m][6][j]) + __expf(acc[m][7][j]);
        lsum[i] += e0 + e1;
      }
    __syncthreads();   // drains prefetch + all reads of cur done before overwrite
  }

  // overlap pass-2's first staging with the linv reduction (post-barrier: safe)
  stage_bf16<64, 64, 256>(Kb, 64, lds, tid);                // K(0) -> Kd[0]
  stage_bf16<64, 64, 256>(Vtb, 1024, lds + 8192, tid);      // V(0) -> Vd[0]
  float linv[8];
#pragma unroll
  for (int i = 0; i < 8; i++) {
    float s = lsum[i];
#pragma unroll
    for (int o = 8; o > 0; o >>= 1) s += __shfl_xor(s, o, 64);
    linv[i] = 1.0f / s;
  }
  __syncthreads();   // staging drained + visible

  // ---- pass 2: recompute S, write attn once, accumulate O = P @ V^T; K,V dbuf ----
  f32x4 acc_o[2][4] = {};
  float* ab = attn + ((long)z << 20) + (long)rowB * 1024;
  for (int kb = 0; kb < 16; kb++) {
    const int cur = kb & 1, nxt = cur ^ 1;
    if (kb < 15) {
      stage_bf16<64, 64, 256>(Kb + (kb + 1) * 4096, 64, lds + nxt * 4096, tid);
      stage_bf16<64, 64, 256>(Vtb + (kb + 1) * 64, 1024, lds + 8192 + nxt * 4096, tid);
    }
    __builtin_amdgcn_sched_barrier(0);   // pin: staging loads issue before this iter's stores
    const u16* Kc = lds + cur * 4096;
    const u16* Vc = lds + 8192 + cur * 4096;
    f32x4 acc[2][4] = {};
    __builtin_amdgcn_s_setprio(1);
#pragma unroll
    for (int kt = 0; kt < 2; kt++) {
      short8 bfr[4];
#pragma unroll
      for (int n = 0; n < 4; n++)
        bfr[n] = *(const short8*)(Kc + (n * 16 + ro) * 64 + kt * 32 + ko8);
#pragma unroll
      for (int m = 0; m < 2; m++)
#pragma unroll
        for (int n = 0; n < 4; n++)
          acc[m][n] = __builtin_amdgcn_mfma_f32_16x16x32_bf16(aq[m][kt], bfr[n], acc[m][n], 0, 0, 0);
    }
    __builtin_amdgcn_s_setprio(0);
    // normalized P: write attn (streaming NT stores) + wave-private swizzled Plds
#pragma unroll
    for (int m = 0; m < 2; m++)
#pragma unroll
      for (int j = 0; j < 4; j++) {
        const int i = m * 4 + j;
        const int ql = qw + m * 16 + (lane >> 4) * 4 + j;   // local q row
        float* rowp = ab + (long)ql * 1024 + kb * 64;
        u16* prow = Pl + ql * 64;
        const int sw = ((ql & 7) << 3);
#pragma unroll
        for (int n = 0; n < 4; n++) {
          const int col = n * 16 + (lane & 15);
          float p = __expf(acc[m][n][j]) * linv[i];
          __builtin_nontemporal_store(p, rowp + col);
          prow[col ^ sw] = f2bf(p);
        }
      }
    // own-wave P writes visible (cross-lane within wave); does NOT touch vmcnt
    asm volatile("s_waitcnt lgkmcnt(0)" ::: "memory");
    __builtin_amdgcn_sched_barrier(0);
    // PV: acc_o += P(own rows, Plds) * V(Vc)
    __builtin_amdgcn_s_setprio(1);
#pragma unroll
    for (int kt = 0; kt < 2; kt++) {
      short8 pa[2], bv[4];
#pragma unroll
      for (int m = 0; m < 2; m++) {
        const int row = qw + m * 16 + ro;
        pa[m] = *(const short8*)(Pl + row * 64 + ((kt * 32 + ko8) ^ ((row & 7) << 3)));
      }
#pragma unroll
      for (int n = 0; n < 4; n++)
        bv[n] = *(const short8*)(Vc + (n * 16 + ro) * 64 + kt * 32 + ko8);
#pragma unroll
      for (int m = 0; m < 2; m++)
#pragma unroll
        for (int n = 0; n < 4; n++)
          acc_o[m][n] = __builtin_amdgcn_mfma_f32_16x16x32_bf16(pa[m], bv[n], acc_o[m][n], 0, 0, 0);
    }
    __builtin_amdgcn_s_setprio(0);
    // COUNTED end-of-iteration barrier: my ds reads done; my 4 staging loads
    // retired (vmcnt(32) leaves only the 32 newest = this iter's NT stores in
    // flight); then rendezvous. Tail kb=15: no loads issued, wait is a no-op.
    asm volatile("s_waitcnt lgkmcnt(0)" ::: "memory");
    __builtin_amdgcn_sched_barrier(0);
    asm volatile("s_waitcnt vmcnt(32)" ::: "memory");
    __builtin_amdgcn_s_barrier();
    __builtin_amdgcn_sched_barrier(0);
  }

  // write Ctx (B,S,E) bf16
  u16* cb = Ctx + ((long)b << 20) + (long)h * 64;
#pragma unroll
  for (int m = 0; m < 2; m++)
#pragma unroll
    for (int j = 0; j < 4; j++) {
      const long s = rowB + qw + m * 16 + (lane >> 4) * 4 + j;
#pragma unroll
      for (int n = 0; n < 4; n++)
        cb[s * 1024 + n * 16 + (lane & 15)] = f2bf(acc_o[m][n][j]);
    }
}

// ---- out projection (all-bf16, BK=32 m97 economics, r16-proven) ----
__global__ __launch_bounds__(256) void outb_kernel(const u16* __restrict__ Ctx,
                                                   const u16* __restrict__ W,
                                                   const float* __restrict__ bias,
                                                   float* __restrict__ Out) {
  __shared__ u16 Alds[128 * 32];
  __shared__ u16 Blds[128 * 32];
  const int tid = threadIdx.x, lane = tid & 63, w = tid >> 6;
  const int wr = (w >> 1) * 64, wc = (w & 1) * 64;
  const long rowB = (long)blockIdx.x * 128;   // fast dim
  const int colB = blockIdx.y * 128;
  f32x4 acc[4][4] = {};
  for (int k0 = 0; k0 < 1024; k0 += 32) {
    stage_bf16<128, 32, 256>(Ctx + rowB * 1024 + k0, 1024, Alds, tid);
    stage_bf16<128, 32, 256>(W + (long)colB * 1024 + k0, 1024, Blds, tid);
    __syncthreads();
    kstep<4, 4, 32>(Alds, Blds, lane, wr, wc, 0, acc);
    __syncthreads();
  }
  const int ro = (lane >> 4) * 4, co = lane & 15;
#pragma unroll
  for (int n = 0; n < 4; n++) {
    const int col = colB + wc + n * 16 + co;
    const float bv = bias[col];
#pragma unroll
    for (int m = 0; m < 4; m++)
#pragma unroll
      for (int j = 0; j < 4; j++) {
        long r = rowB + wr + m * 16 + ro + j;
        __builtin_nontemporal_store(acc[m][n][j] + bv, Out + r * 1024 + col);
      }
  }
}

extern "C" void kernel_launch(void* const* d_in, const int* in_sizes, int n_in,
                              void* d_out, int out_size, void* d_ws, size_t ws_size,
                              hipStream_t stream) {
  const float* query = (const float*)d_in[0];
  const float* key   = (const float*)d_in[1];
  const float* value = (const float*)d_in[2];
  const float* q_w   = (const float*)d_in[3];
  const float* q_b   = (const float*)d_in[4];
  const float* k_w   = (const float*)d_in[5];
  const float* k_b   = (const float*)d_in[6];
  const float* v_w   = (const float*)d_in[7];
  const float* v_b   = (const float*)d_in[8];
  const float* out_w = (const float*)d_in[9];
  const float* out_b = (const float*)d_in[10];

  const long MB = 1048576L;
  char* ws = (char*)d_ws;
  u16* Qp  = (u16*)(ws);             // (B,H,S,D) bf16 (0.125-scaled), 16 MB
  u16* Kp  = (u16*)(ws + 16 * MB);   // (B,H,S,D) 16 MB
  u16* Vt  = (u16*)(ws + 32 * MB);   // (B,H,D,S) 16 MB (written directly by proj z=2)
  u16* Qb  = (u16*)(ws + 48 * MB);   // bf16 query input   } consecutive, stride 16 MB
  u16* Kb  = (u16*)(ws + 64 * MB);   // bf16 key input     }
  u16* Vb  = (u16*)(ws + 80 * MB);   // bf16 value input   }
  u16* Ctx = (u16*)(ws + 64 * MB);   // (B,S,E) aliases Kb (dead after proj3)
  u16* Wq  = (u16*)(ws + 96 * MB);   // 2 MB each, consecutive
  u16* Wk  = (u16*)(ws + 98 * MB);
  u16* Wv  = (u16*)(ws + 100 * MB);
  u16* Wo  = (u16*)(ws + 102 * MB);  // total 104 MB

  float* attn = (float*)d_out;                       // [8,16,1024,1024]
  float* outp = (float*)d_out + 134217728L;          // [8,1024,1024]

  CvtArgs ca;
  ca.s[0] = query; ca.d[0] = Qb; ca.n8[0] = 1048576;
  ca.s[1] = key;   ca.d[1] = Kb; ca.n8[1] = 1048576;
  ca.s[2] = value; ca.d[2] = Vb; ca.n8[2] = 1048576;
  ca.s[3] = q_w;   ca.d[3] = Wq; ca.n8[3] = 131072;
  ca.s[4] = k_w;   ca.d[4] = Wk; ca.n8[4] = 131072;
  ca.s[5] = v_w;   ca.d[5] = Wv; ca.n8[5] = 131072;
  ca.s[6] = out_w; ca.d[6] = Wo; ca.n8[6] = 131072;

  Biases bs;
  bs.p[0] = q_b; bs.p[1] = k_b; bs.p[2] = v_b;

  cvt_all<<<dim3(2048, 7), dim3(256), 0, stream>>>(ca);
  proj3_kernel<<<dim3(64, 8, 3), dim3(256), 0, stream>>>(Qb, Wq, bs, Qp);
  flash_kernel<<<dim3(128, 8), dim3(256), 0, stream>>>(Qp, Kp, Vt, attn, Ctx);
  outb_kernel<<<dim3(64, 8), dim3(256), 0, stream>>>(Ctx, Wo, out_b, outp);
}